// Round 1
// baseline (701.603 us; speedup 1.0000x reference)
//
#include <hip/hip_runtime.h>
#include <math.h>

// Problem constants (fixed by the reference)
#define BB 8
#define LQ 512
#define LK 512
#define DD 64
constexpr float INV_TEMP = 1.0f / 8.0f;  // 1/sqrt(64)

// One block per (b,i) row. 256 threads = 4 waves. Each wave is 4 groups of 16
// lanes; group handles one j per iteration, lane t loads float4 of dims
// [4t,4t+3]. Online softmax per group (16 states), merged via LDS.
__global__ __launch_bounds__(256) void attn_bias_kernel(
    const float* __restrict__ q,
    const float* __restrict__ k,
    const float* __restrict__ v,
    const float* __restrict__ bias,
    float* __restrict__ out_emb,   // [B*LQ*D]
    float* __restrict__ out_attn)  // [B*LQ*LK]
{
    const int row  = blockIdx.x;        // b*LQ + i
    const int b    = row >> 9;          // /LQ
    const int tid  = threadIdx.x;
    const int wave = tid >> 6;
    const int lane = tid & 63;
    const int jj   = lane >> 4;         // group within wave (0..3)
    const int t    = lane & 15;         // lane within group
    const int g    = (wave << 2) | jj;  // global group id (0..15)

    __shared__ float  s_lds[LK];        // raw scores (pre-softmax)
    __shared__ float4 o_lds4[16 * 16];  // 16 groups x 64 dims
    __shared__ float  m_lds[16];
    __shared__ float  l_lds[16];

    // q fragment: lane t holds q[4t..4t+3] (same in every group)
    const float4 qf = reinterpret_cast<const float4*>(q + row * DD)[t];

    const float4* bias_row = reinterpret_cast<const float4*>(
        bias + (size_t)row * (LK * DD));
    const float4* k_b = reinterpret_cast<const float4*>(k + b * (LK * DD));
    const float4* v_b = reinterpret_cast<const float4*>(v + b * (LK * DD));

    float  m = -1e30f;
    float  l = 0.f;
    float4 o = make_float4(0.f, 0.f, 0.f, 0.f);

    // group g handles j = it*16 + g
    #pragma unroll 4
    for (int it = 0; it < LK / 16; ++it) {
        const int j   = (it << 4) + g;
        const int idx = j * (DD / 4) + t;   // float4 index within a row
        const float4 bv = bias_row[idx];
        const float4 kv = k_b[idx];
        const float4 vv = v_b[idx];

        float part = qf.x * (kv.x + bv.x)
                   + qf.y * (kv.y + bv.y)
                   + qf.z * (kv.z + bv.z)
                   + qf.w * (kv.w + bv.w);
        // 16-lane reduction (masks < 16 stay inside the group)
        part += __shfl_xor(part, 1);
        part += __shfl_xor(part, 2);
        part += __shfl_xor(part, 4);
        part += __shfl_xor(part, 8);
        const float s = part * INV_TEMP;
        if (t == 0) s_lds[j] = s;

        const float m_new = fmaxf(m, s);
        const float w     = __expf(s - m_new);
        const float alpha = __expf(m - m_new);
        l = l * alpha + w;
        o.x = o.x * alpha + w * (vv.x + bv.x);
        o.y = o.y * alpha + w * (vv.y + bv.y);
        o.z = o.z * alpha + w * (vv.z + bv.z);
        o.w = o.w * alpha + w * (vv.w + bv.w);
        m = m_new;
    }

    // publish per-group state
    o_lds4[g * 16 + t] = o;
    if (t == 0) { m_lds[g] = m; l_lds[g] = l; }
    __syncthreads();

    // merge 16 online-softmax states (every thread computes M, L — cheap)
    float M = -1e30f;
    #pragma unroll
    for (int gg = 0; gg < 16; ++gg) M = fmaxf(M, m_lds[gg]);
    float L = 0.f;
    #pragma unroll
    for (int gg = 0; gg < 16; ++gg) L += l_lds[gg] * __expf(m_lds[gg] - M);
    const float invL = 1.0f / L;

    // attn output: coalesced, 2 elems/thread
    float* attn_row = out_attn + (size_t)row * LK;
    for (int j = tid; j < LK; j += 256)
        attn_row[j] = __expf(s_lds[j] - M) * invL;

    // emb output: first 64 threads each own one dim
    if (tid < DD) {
        const float* o_f = reinterpret_cast<const float*>(o_lds4);
        float O = 0.f;
        #pragma unroll
        for (int gg = 0; gg < 16; ++gg)
            O += o_f[gg * DD + tid] * __expf(m_lds[gg] - M);
        out_emb[row * DD + tid] = O * invL;
    }
}

extern "C" void kernel_launch(void* const* d_in, const int* in_sizes, int n_in,
                              void* d_out, int out_size, void* d_ws, size_t ws_size,
                              hipStream_t stream) {
    const float* q    = (const float*)d_in[0];
    const float* k    = (const float*)d_in[1];
    const float* v    = (const float*)d_in[2];
    const float* bias = (const float*)d_in[3];
    float* out_emb  = (float*)d_out;                  // B*LQ*D
    float* out_attn = (float*)d_out + BB * LQ * DD;   // B*LQ*LK

    attn_bias_kernel<<<BB * LQ, 256, 0, stream>>>(q, k, v, bias, out_emb, out_attn);
}